// Round 10
// baseline (38.185 us; speedup 1.0000x reference)
//
#include <hip/hip_runtime.h>
#include <math.h>

#define N_  2
#define A_  360
#define M_  512
#define NP_ 32
#define PS_ 64
#define RT_ 8             // 8x8 pixel region per block
#define W_  12            // float2 pairs per window (span <= 9.9, +interp +slack)
#define TEAMS 8
#define TA_ 45            // angles per team (8 x 45 = 360)
#define TPAD 48           // padded table stride (16B-aligned float4 groups)

// 512-thread blocks = 8 wave-aligned teams; each team = one wave = the whole
// 8x8 region, covering 45 angles. Windows staged as {g0, g1-g0} pairs so the
// divergent gather is ONE aligned ds_read_b64. LDS = 39,168 B -> 4 blocks/CU
// (32 waves/CU: ~32 in-flight gathers/SIMD covers DS latency, unlike R9).
__global__ __launch_bounds__(512) void fbp_kernel(
    const float* __restrict__ sino,   // (N,1,A,M)
    const float* __restrict__ theta,  // (A)
    const float* __restrict__ cxs,    // (NP)
    const float* __restrict__ cys,    // (NP)
    float* __restrict__ out)          // (N,NP,PS,PS)
{
    __shared__ float2 win2[A_ * W_];                    // 34560 B: {g0, g1-g0}
    __shared__ alignas(16) float2 csyT[TEAMS][TPAD];    //  3072 B: {cos*h, sin*h}
    __shared__ alignas(16) float  ofT[TEAMS][TPAD];     //  1536 B: half - lo
                                                        // total 39168 B

    const float half = 255.5f;        // (M-1)/2
    const int tid = threadIdx.x;

    const int bid    = blockIdx.x;
    const int region = bid & 63;            // 8x8 regions per 64x64 patch
    const int p      = (bid >> 6) & (NP_ - 1);
    const int n      = bid >> 11;
    const int ri     = (region >> 3) << 3;
    const int rj     = (region &  7) << 3;

    const float cx = cxs[p];
    const float cy = cys[p];

    // Region corner coords (same op sequence as per-pixel => covering bounds)
    const float gX0 = ((float)(ri     - PS_ / 2) + cx) / half - 1.0f;
    const float gX1 = ((float)(ri + 7 - PS_ / 2) + cx) / half - 1.0f;
    const float gy0 = ((float)(rj     - PS_ / 2) + cy) / half - 1.0f;
    const float gy1 = ((float)(rj + 7 - PS_ / 2) + cy) / half - 1.0f;

    // Phase A: per-angle trig + window origin, written into team-padded tables
    if (tid < A_) {
        const float th  = theta[tid];
        const float csx = cosf(th) * half;
        const float csy = sinf(th) * half;
        const float t0  = fmaf(-gy0, csy, half);
        const float t1  = fmaf(-gy1, csy, half);
        const float u00 = fmaf(gX0, csx, t0);
        const float u10 = fmaf(gX1, csx, t0);
        const float u01 = fmaf(gX0, csx, t1);
        const float u11 = fmaf(gX1, csx, t1);
        const float lof = floorf(fminf(fminf(u00, u10), fminf(u01, u11)));
        const int   tm  = tid / TA_;
        const int   al  = tid - tm * TA_;
        csyT[tm][al] = make_float2(csx, csy);
        ofT[tm][al]  = half - lof;          // exact: lof integer, half = 255.5
    }
    __syncthreads();

    // Phase B: stage pair-windows {g0, g1-g0} (global reads, linear LDS writes)
    const float* __restrict__ srow = sino + n * (A_ * M_);
    for (int e = tid; e < A_ * W_; e += 512) {
        const int a  = e / W_;
        const int k  = e - a * W_;
        const int tm = a / TA_;
        const int al = a - tm * TA_;
        const int lo = (int)(half - ofT[tm][al]);   // exact recovery
        const int i0 = min(max(lo + k,     0), M_ - 1);
        const int i1 = min(max(lo + k + 1, 0), M_ - 1);
        const float g0 = srow[a * M_ + i0];
        const float g1 = srow[a * M_ + i1];
        win2[e] = make_float2(g0, g1 - g0);
    }
    __syncthreads();

    // Phase C: each team (one wave) does 45 angles for all 64 region pixels
    const int team = tid >> 6;
    const int lane = tid & 63;
    const int i    = ri + (lane >> 3);
    const int j    = rj + (lane & 7);

    const float gX  = ((float)(i - PS_ / 2) + cx) / half - 1.0f;
    const float gy  = ((float)(j - PS_ / 2) + cy) / half - 1.0f;
    const float ngy = -gy;

    const float4* __restrict__ csy4 = (const float4*)&csyT[team][0];
    const float4* __restrict__ of4  = (const float4*)&ofT[team][0];
    const float2* __restrict__ wbase = win2 + team * (TA_ * W_);

    float accG = 0.0f;
    float accW = 0.0f;

    #pragma unroll 4
    for (int g = 0; g < 11; ++g) {          // 11 groups x 4 angles = al 0..43
        const float4 cA = csy4[2 * g];      // {cs0, sy0, cs1, sy1}
        const float4 cB = csy4[2 * g + 1];  // {cs2, sy2, cs3, sy3}
        const float4 o4 = of4[g];
        const float2* wp = wbase + g * (4 * W_);

        {   // angle al = 4g
            float u = fmaf(gX, cA.x, fmaf(ngy, cA.y, o4.x));
            u = fminf(fmaxf(u, 0.0f), 11.999f);
            const float2 gg = wp[(int)u];
            accG += gg.x;  accW = fmaf(__builtin_amdgcn_fractf(u), gg.y, accW);
        }
        {   // al = 4g+1
            float u = fmaf(gX, cA.z, fmaf(ngy, cA.w, o4.y));
            u = fminf(fmaxf(u, 0.0f), 11.999f);
            const float2 gg = wp[W_ + (int)u];
            accG += gg.x;  accW = fmaf(__builtin_amdgcn_fractf(u), gg.y, accW);
        }
        {   // al = 4g+2
            float u = fmaf(gX, cB.x, fmaf(ngy, cB.y, o4.z));
            u = fminf(fmaxf(u, 0.0f), 11.999f);
            const float2 gg = wp[2 * W_ + (int)u];
            accG += gg.x;  accW = fmaf(__builtin_amdgcn_fractf(u), gg.y, accW);
        }
        {   // al = 4g+3
            float u = fmaf(gX, cB.z, fmaf(ngy, cB.w, o4.w));
            u = fminf(fmaxf(u, 0.0f), 11.999f);
            const float2 gg = wp[3 * W_ + (int)u];
            accG += gg.x;  accW = fmaf(__builtin_amdgcn_fractf(u), gg.y, accW);
        }
    }
    {   // tail angle al = 44
        const float2 cst = csyT[team][44];
        const float  of  = ofT[team][44];
        float u = fmaf(gX, cst.x, fmaf(ngy, cst.y, of));
        u = fminf(fmaxf(u, 0.0f), 11.999f);
        const float2 gg = wbase[44 * W_ + (int)u];
        accG += gg.x;  accW = fmaf(__builtin_amdgcn_fractf(u), gg.y, accW);
    }

    float part = accG + accW;

    // Cross-team reduction, reusing win2 space (all gathers done after barrier)
    __syncthreads();
    float* red = (float*)win2;
    if (team != 0) red[(team - 1) * 64 + lane] = part;
    __syncthreads();
    if (team == 0) {
        #pragma unroll
        for (int q = 0; q < 7; ++q) part += red[q * 64 + lane];
        const float inside = (fmaf(gX, gX, gy * gy) <= 1.0f) ? 1.0f : 0.0f;
        const float scale  = (float)(M_PI / (2.0 * (double)A_));
        out[(((n * NP_) + p) * PS_ + i) * PS_ + j] = part * inside * scale;
    }
}

extern "C" void kernel_launch(void* const* d_in, const int* in_sizes, int n_in,
                              void* d_out, int out_size, void* d_ws, size_t ws_size,
                              hipStream_t stream) {
    const float* sino  = (const float*)d_in[0];
    const float* theta = (const float*)d_in[1];
    const float* cxs   = (const float*)d_in[2];
    const float* cys   = (const float*)d_in[3];
    float* out = (float*)d_out;

    const int blocks = N_ * NP_ * ((PS_ / RT_) * (PS_ / RT_));  // 4096
    fbp_kernel<<<dim3(blocks), dim3(512), 0, stream>>>(sino, theta, cxs, cys, out);
}

// Round 11
// 37.718 us; speedup vs baseline: 1.0124x; 1.0124x over previous
//
#include <hip/hip_runtime.h>
#include <math.h>

#define N_  2
#define A_  360
#define M_  512
#define NP_ 32
#define PS_ 64
#define TEAM_A 180
#define W_  24            // float2 pairs per LDS window (16x16 span <=21.3 +interp +slack)
#define LDSG 23           // even angle-groups per team -> LDS path (g=0,2,..,44)
#define NWANG (2 * LDSG * 4)   // 184 windowed angles

// Pre-kernel output: 8B-aligned {g0, g1-g0} pairs for every sinogram sample.
__global__ __launch_bounds__(256) void make_pairs(
    const float* __restrict__ sino, float2* __restrict__ pairs)
{
    const int idx = blockIdx.x * 256 + threadIdx.x;   // < N_*A_*M_
    const int k   = idx & (M_ - 1);
    const float s0 = sino[idx];
    const float s1 = (k < M_ - 1) ? sino[idx + 1] : s0;
    pairs[idx] = make_float2(s0, s1 - s0);
}

// Main kernel: R7 structure (16x16 region, 2 angle-teams of 256 threads).
// Per team, 45 groups of 4 angles alternate: even groups gather from LDS
// pair-windows (1 ds_read_b64), odd groups gather from the global pair
// array (1 global_load_dwordx2) -> DS and TA pipes run concurrently.
__global__ __launch_bounds__(512) void fbp_split(
    const float* __restrict__ sino,   // (N,1,A,M)
    const float2* __restrict__ pairs, // (N,A,M) {g0, g1-g0}
    const float* __restrict__ theta,  // (A)
    const float* __restrict__ cxs,    // (NP)
    const float* __restrict__ cys,    // (NP)
    float* __restrict__ out)          // (N,NP,PS,PS)
{
    __shared__ float2 win2[NWANG * W_];            // 35328 B: {g0, g1-g0}
    __shared__ alignas(16) float csA[A_];          // 1440 B: cos*half
    __shared__ alignas(16) float syA[A_];          // 1440 B: sin*half
    __shared__ alignas(16) float ofA[192];         //  768 B: half - lo (windowed)
    __shared__ float red[256];                     // 1024 B => 40000 B -> 4 blk/CU

    const float half = 255.5f;
    const int tid = threadIdx.x;

    const int bid    = blockIdx.x;
    const int region = bid & 15;
    const int p      = (bid >> 4) & (NP_ - 1);
    const int n      = bid >> 9;
    const int ri     = (region >> 2) << 4;
    const int rj     = (region &  3) << 4;

    const float cx = cxs[p];
    const float cy = cys[p];

    const float gX0 = ((float)(ri      - PS_ / 2) + cx) / half - 1.0f;
    const float gX1 = ((float)(ri + 15 - PS_ / 2) + cx) / half - 1.0f;
    const float gy0 = ((float)(rj      - PS_ / 2) + cy) / half - 1.0f;
    const float gy1 = ((float)(rj + 15 - PS_ / 2) + cy) / half - 1.0f;

    // Phase A: trig for all angles; window origin for even-group angles
    if (tid < A_) {
        const float th  = theta[tid];
        const float csx = cosf(th) * half;
        const float csy = sinf(th) * half;
        csA[tid] = csx;
        syA[tid] = csy;
        const int team = tid / TEAM_A;
        const int al   = tid - team * TEAM_A;
        const int g    = al >> 2;
        if (!(g & 1)) {
            const float t0  = fmaf(-gy0, csy, half);
            const float t1  = fmaf(-gy1, csy, half);
            const float u00 = fmaf(gX0, csx, t0);
            const float u10 = fmaf(gX1, csx, t0);
            const float u01 = fmaf(gX0, csx, t1);
            const float u11 = fmaf(gX1, csx, t1);
            const float lof = floorf(fminf(fminf(u00, u10), fminf(u01, u11)));
            const int   wa  = (team * LDSG + (g >> 1)) * 4 + (al & 3);
            ofA[wa] = half - lof;              // exact: lof integer
        }
    }
    __syncthreads();

    // Phase B: stage pair-windows {g0, g1-g0} for the 184 windowed angles
    const float* __restrict__ srow = sino + n * (A_ * M_);
    for (int e = tid; e < NWANG * W_; e += 512) {
        const int wa = e / W_;
        const int k  = e - wa * W_;
        const int tw = wa / (LDSG * 4);
        const int r  = wa - tw * (LDSG * 4);
        const int a  = tw * TEAM_A + ((r >> 2) << 3) + (r & 3);  // even group angles
        const int lo = (int)(half - ofA[wa]);
        const int i0 = min(max(lo + k,     0), M_ - 1);
        const int i1 = min(max(lo + k + 1, 0), M_ - 1);
        const float g0 = srow[a * M_ + i0];
        const float g1 = srow[a * M_ + i1];
        win2[e] = make_float2(g0, g1 - g0);
    }
    __syncthreads();

    // Phase C: 180 angles per team, gathers alternating LDS / global-pair
    const int team = tid >> 8;
    const int t    = tid & 255;
    const int i    = ri + (t >> 4);
    const int j    = rj + (t & 15);

    const float gX  = ((float)(i - PS_ / 2) + cx) / half - 1.0f;
    const float gy  = ((float)(j - PS_ / 2) + cy) / half - 1.0f;
    const float ngy = -gy;

    const float4* __restrict__ cs4 = (const float4*)csA;
    const float4* __restrict__ sy4 = (const float4*)syA;
    const float4* __restrict__ of4 = (const float4*)ofA;

    const int     base_g  = team * 45;
    const float2* wbase   = win2 + team * (LDSG * 4 * W_);
    const float2* __restrict__ pairs_n = pairs + n * (A_ * M_);

    float accG = 0.0f;
    float accW = 0.0f;

    #pragma unroll 2
    for (int gg = 0; gg < 22; ++gg) {
        // ---- global group (odd): angles team*180 + 8gg+4 .. +7 ----
        const float4 cg = cs4[base_g + 2 * gg + 1];
        const float4 sg = sy4[base_g + 2 * gg + 1];
        float u0 = fmaf(gX, cg.x, fmaf(ngy, sg.x, half));
        float u1 = fmaf(gX, cg.y, fmaf(ngy, sg.y, half));
        float u2 = fmaf(gX, cg.z, fmaf(ngy, sg.z, half));
        float u3 = fmaf(gX, cg.w, fmaf(ngy, sg.w, half));
        u0 = fminf(fmaxf(u0, 0.0f), 510.999f);
        u1 = fminf(fmaxf(u1, 0.0f), 510.999f);
        u2 = fminf(fmaxf(u2, 0.0f), 510.999f);
        u3 = fminf(fmaxf(u3, 0.0f), 510.999f);
        const float2* pg = pairs_n + (team * TEAM_A + 8 * gg + 4) * M_;
        const float2 pa = pg[(int)u0];
        const float2 pb = pg[M_     + (int)u1];
        const float2 pc = pg[2 * M_ + (int)u2];
        const float2 pd = pg[3 * M_ + (int)u3];
        const float w0 = __builtin_amdgcn_fractf(u0);
        const float w1 = __builtin_amdgcn_fractf(u1);
        const float w2 = __builtin_amdgcn_fractf(u2);
        const float w3 = __builtin_amdgcn_fractf(u3);

        // ---- LDS group (even): angles team*180 + 8gg .. +3 ----
        const float4 cl = cs4[base_g + 2 * gg];
        const float4 sl = sy4[base_g + 2 * gg];
        const float4 o4 = of4[team * LDSG + gg];
        const float2* wp = wbase + gg * (4 * W_);
        {
            float u = fmaf(gX, cl.x, fmaf(ngy, sl.x, o4.x));
            u = fminf(fmaxf(u, 0.0f), 22.999f);
            const float2 gg2 = wp[(int)u];
            accG += gg2.x;  accW = fmaf(__builtin_amdgcn_fractf(u), gg2.y, accW);
        }
        {
            float u = fmaf(gX, cl.y, fmaf(ngy, sl.y, o4.y));
            u = fminf(fmaxf(u, 0.0f), 22.999f);
            const float2 gg2 = wp[W_ + (int)u];
            accG += gg2.x;  accW = fmaf(__builtin_amdgcn_fractf(u), gg2.y, accW);
        }
        {
            float u = fmaf(gX, cl.z, fmaf(ngy, sl.z, o4.z));
            u = fminf(fmaxf(u, 0.0f), 22.999f);
            const float2 gg2 = wp[2 * W_ + (int)u];
            accG += gg2.x;  accW = fmaf(__builtin_amdgcn_fractf(u), gg2.y, accW);
        }
        {
            float u = fmaf(gX, cl.w, fmaf(ngy, sl.w, o4.w));
            u = fminf(fmaxf(u, 0.0f), 22.999f);
            const float2 gg2 = wp[3 * W_ + (int)u];
            accG += gg2.x;  accW = fmaf(__builtin_amdgcn_fractf(u), gg2.y, accW);
        }

        // ---- consume global results ----
        accG += pa.x;  accW = fmaf(w0, pa.y, accW);
        accG += pb.x;  accW = fmaf(w1, pb.y, accW);
        accG += pc.x;  accW = fmaf(w2, pc.y, accW);
        accG += pd.x;  accW = fmaf(w3, pd.y, accW);
    }

    // ---- tail: last LDS group (g = 44, lgi = 22) ----
    {
        const float4 cl = cs4[base_g + 44];
        const float4 sl = sy4[base_g + 44];
        const float4 o4 = of4[team * LDSG + 22];
        const float2* wp = wbase + 22 * (4 * W_);
        {
            float u = fmaf(gX, cl.x, fmaf(ngy, sl.x, o4.x));
            u = fminf(fmaxf(u, 0.0f), 22.999f);
            const float2 gg2 = wp[(int)u];
            accG += gg2.x;  accW = fmaf(__builtin_amdgcn_fractf(u), gg2.y, accW);
        }
        {
            float u = fmaf(gX, cl.y, fmaf(ngy, sl.y, o4.y));
            u = fminf(fmaxf(u, 0.0f), 22.999f);
            const float2 gg2 = wp[W_ + (int)u];
            accG += gg2.x;  accW = fmaf(__builtin_amdgcn_fractf(u), gg2.y, accW);
        }
        {
            float u = fmaf(gX, cl.z, fmaf(ngy, sl.z, o4.z));
            u = fminf(fmaxf(u, 0.0f), 22.999f);
            const float2 gg2 = wp[2 * W_ + (int)u];
            accG += gg2.x;  accW = fmaf(__builtin_amdgcn_fractf(u), gg2.y, accW);
        }
        {
            float u = fmaf(gX, cl.w, fmaf(ngy, sl.w, o4.w));
            u = fminf(fmaxf(u, 0.0f), 22.999f);
            const float2 gg2 = wp[3 * W_ + (int)u];
            accG += gg2.x;  accW = fmaf(__builtin_amdgcn_fractf(u), gg2.y, accW);
        }
    }

    const float part = accG + accW;
    if (team == 1) red[t] = part;
    __syncthreads();
    if (team == 0) {
        const float inside = (fmaf(gX, gX, gy * gy) <= 1.0f) ? 1.0f : 0.0f;
        const float scale  = (float)(M_PI / (2.0 * (double)A_));
        out[(((n * NP_) + p) * PS_ + i) * PS_ + j] =
            (part + red[t]) * inside * scale;
    }
}

// Fallback (= R7 kernel, 29 us known-good) if d_ws is too small for pairs.
__global__ __launch_bounds__(512) void fbp_lds_only(
    const float* __restrict__ sino, const float* __restrict__ theta,
    const float* __restrict__ cxs,  const float* __restrict__ cys,
    float* __restrict__ out)
{
    __shared__ float win[A_ * W_];
    __shared__ alignas(16) float csA[A_];
    __shared__ alignas(16) float syA[A_];
    __shared__ alignas(16) float ofA[A_];
    __shared__ float red[256];

    const float half = 255.5f;
    const int tid = threadIdx.x;
    const int bid    = blockIdx.x;
    const int region = bid & 15;
    const int p      = (bid >> 4) & (NP_ - 1);
    const int n      = bid >> 9;
    const int ri     = (region >> 2) << 4;
    const int rj     = (region &  3) << 4;
    const float cx = cxs[p];
    const float cy = cys[p];
    const float gX0 = ((float)(ri      - PS_ / 2) + cx) / half - 1.0f;
    const float gX1 = ((float)(ri + 15 - PS_ / 2) + cx) / half - 1.0f;
    const float gy0 = ((float)(rj      - PS_ / 2) + cy) / half - 1.0f;
    const float gy1 = ((float)(rj + 15 - PS_ / 2) + cy) / half - 1.0f;

    if (tid < A_) {
        const float th  = theta[tid];
        const float csx = cosf(th) * half;
        const float csy = sinf(th) * half;
        const float t0  = fmaf(-gy0, csy, half);
        const float t1  = fmaf(-gy1, csy, half);
        const float u00 = fmaf(gX0, csx, t0);
        const float u10 = fmaf(gX1, csx, t0);
        const float u01 = fmaf(gX0, csx, t1);
        const float u11 = fmaf(gX1, csx, t1);
        const float lof = floorf(fminf(fminf(u00, u10), fminf(u01, u11)));
        csA[tid] = csx;  syA[tid] = csy;  ofA[tid] = half - lof;
    }
    __syncthreads();

    const float* __restrict__ srow = sino + n * (A_ * M_);
    for (int e = tid; e < A_ * W_; e += 512) {
        const int a  = e / W_;
        const int k  = e - a * W_;
        const int lo = (int)(half - ofA[a]);
        const int idx = min(max(lo + k, 0), M_ - 1);
        win[e] = srow[a * M_ + idx];
    }
    __syncthreads();

    const int team = tid >> 8;
    const int t    = tid & 255;
    const int i    = ri + (t >> 4);
    const int j    = rj + (t & 15);
    const float gX  = ((float)(i - PS_ / 2) + cx) / half - 1.0f;
    const float gy  = ((float)(j - PS_ / 2) + cy) / half - 1.0f;
    const float ngy = -gy;

    const int gbase = team * (TEAM_A / 4);
    const float4* __restrict__ cs4 = (const float4*)csA;
    const float4* __restrict__ sy4 = (const float4*)syA;
    const float4* __restrict__ of4 = (const float4*)ofA;
    float accG = 0.0f, accW = 0.0f;
    const float* wp0 = win + team * (TEAM_A * W_);

    #pragma unroll 3
    for (int g = 0; g < TEAM_A / 4; ++g) {
        const float4 c4 = cs4[gbase + g];
        const float4 s4 = sy4[gbase + g];
        const float4 o4 = of4[gbase + g];
        const float* wp = wp0 + g * (4 * W_);
        {
            float u = fmaf(gX, c4.x, fmaf(ngy, s4.x, o4.x));
            u = fminf(fmaxf(u, 0.0f), 22.999f);
            const int k = (int)u;
            const float w = __builtin_amdgcn_fractf(u);
            const float g0 = wp[k], g1 = wp[k + 1];
            accG += g0;  accW = fmaf(w, g1 - g0, accW);
        }
        {
            float u = fmaf(gX, c4.y, fmaf(ngy, s4.y, o4.y));
            u = fminf(fmaxf(u, 0.0f), 22.999f);
            const int k = (int)u;
            const float w = __builtin_amdgcn_fractf(u);
            const float g0 = wp[W_ + k], g1 = wp[W_ + k + 1];
            accG += g0;  accW = fmaf(w, g1 - g0, accW);
        }
        {
            float u = fmaf(gX, c4.z, fmaf(ngy, s4.z, o4.z));
            u = fminf(fmaxf(u, 0.0f), 22.999f);
            const int k = (int)u;
            const float w = __builtin_amdgcn_fractf(u);
            const float g0 = wp[2 * W_ + k], g1 = wp[2 * W_ + k + 1];
            accG += g0;  accW = fmaf(w, g1 - g0, accW);
        }
        {
            float u = fmaf(gX, c4.w, fmaf(ngy, s4.w, o4.w));
            u = fminf(fmaxf(u, 0.0f), 22.999f);
            const int k = (int)u;
            const float w = __builtin_amdgcn_fractf(u);
            const float g0 = wp[3 * W_ + k], g1 = wp[3 * W_ + k + 1];
            accG += g0;  accW = fmaf(w, g1 - g0, accW);
        }
    }

    const float part = accG + accW;
    if (team == 1) red[t] = part;
    __syncthreads();
    if (team == 0) {
        const float inside = (fmaf(gX, gX, gy * gy) <= 1.0f) ? 1.0f : 0.0f;
        const float scale  = (float)(M_PI / (2.0 * (double)A_));
        out[(((n * NP_) + p) * PS_ + i) * PS_ + j] =
            (part + red[t]) * inside * scale;
    }
}

extern "C" void kernel_launch(void* const* d_in, const int* in_sizes, int n_in,
                              void* d_out, int out_size, void* d_ws, size_t ws_size,
                              hipStream_t stream) {
    const float* sino  = (const float*)d_in[0];
    const float* theta = (const float*)d_in[1];
    const float* cxs   = (const float*)d_in[2];
    const float* cys   = (const float*)d_in[3];
    float* out = (float*)d_out;

    const size_t pairs_bytes = (size_t)N_ * A_ * M_ * sizeof(float2);  // 2.95 MB
    const int blocks = N_ * NP_ * (PS_ * PS_ / 256);  // 1024

    if (ws_size >= pairs_bytes) {
        float2* pairs = (float2*)d_ws;
        make_pairs<<<dim3(N_ * A_ * M_ / 256), dim3(256), 0, stream>>>(sino, pairs);
        fbp_split<<<dim3(blocks), dim3(512), 0, stream>>>(sino, pairs, theta, cxs, cys, out);
    } else {
        fbp_lds_only<<<dim3(blocks), dim3(512), 0, stream>>>(sino, theta, cxs, cys, out);
    }
}

// Round 12
// 31.384 us; speedup vs baseline: 1.2167x; 1.2018x over previous
//
#include <hip/hip_runtime.h>
#include <math.h>

#define N_  2
#define A_  360
#define M_  512
#define NP_ 32
#define PS_ 64
#define W_  24          // float2 pairs per window (16x16 span <= 21.3 + interp + slack)
#define PASS_A 180      // angles staged per pass
#define CHUNK_A 45      // angles per thread-chunk (4 chunks x 45 x 2 passes = 360... per chunk 90)

// 512-thread blocks over a 16x16 region. Each thread owns TWO j-adjacent
// pixels; since u_{j+1} = u_j - sin(theta) and sin>=0, floor(u_b)=k2 implies
// k_a in {k2,k2+1}: ONE ds_read2_b64 of pairs {k2,k2+1} serves both pixels.
// 4 angle-chunks x 128 pixel-pairs; 2 staging passes of 180 angles keep
// pair-windows at 34.5 KB -> 40,320 B total LDS -> 4 blocks/CU.
__global__ __launch_bounds__(512) void fbp_pair(
    const float* __restrict__ sino,   // (N,1,A,M)
    const float* __restrict__ theta,  // (A)
    const float* __restrict__ cxs,    // (NP)
    const float* __restrict__ cys,    // (NP)
    float* __restrict__ out)          // (N,NP,PS,PS)
{
    __shared__ float2 win2[PASS_A * W_];        // 34560 B: {g0, g1-g0}
    __shared__ alignas(16) float4 tab[A_];      //  5760 B: {csx, csy, off, sn}

    const float half = 255.5f;        // (M-1)/2
    const int tid = threadIdx.x;

    const int bid    = blockIdx.x;
    const int region = bid & 15;
    const int p      = (bid >> 4) & (NP_ - 1);
    const int n      = bid >> 9;
    const int ri     = (region >> 2) << 4;
    const int rj     = (region &  3) << 4;

    const float cx = cxs[p];
    const float cy = cys[p];

    // Region corner coords (same op sequence as per-pixel => covering bounds)
    const float gX0 = ((float)(ri      - PS_ / 2) + cx) / half - 1.0f;
    const float gX1 = ((float)(ri + 15 - PS_ / 2) + cx) / half - 1.0f;
    const float gy0 = ((float)(rj      - PS_ / 2) + cy) / half - 1.0f;
    const float gy1 = ((float)(rj + 15 - PS_ / 2) + cy) / half - 1.0f;

    // Phase A: per-angle {cos*half, sin*half, half-lo, sin}
    if (tid < A_) {
        const float th = theta[tid];
        const float c  = cosf(th);
        const float s  = sinf(th);
        const float csx = c * half;
        const float csy = s * half;
        const float t0  = fmaf(-gy0, csy, half);
        const float t1  = fmaf(-gy1, csy, half);
        const float u00 = fmaf(gX0, csx, t0);
        const float u10 = fmaf(gX1, csx, t0);
        const float u01 = fmaf(gX0, csx, t1);
        const float u11 = fmaf(gX1, csx, t1);
        const float lof = floorf(fminf(fminf(u00, u10), fminf(u01, u11)));
        tab[tid] = make_float4(csx, csy, half - lof, s);   // half-lo exact
    }
    __syncthreads();

    // Pixel-pair assignment: chunk = which 45-angle slice, pp = pixel pair
    const int chunk = tid >> 7;            // 0..3
    const int pp    = tid & 127;
    const int i     = ri + (pp >> 3);
    const int jp    = rj + ((pp & 7) << 1);   // j of pixel a; pixel b = jp+1

    const float gXc  = ((float)(i  - PS_ / 2) + cx) / half - 1.0f;
    const float gyA  = ((float)(jp - PS_ / 2) + cy) / half - 1.0f;
    const float ngyA = -gyA;

    float aG1 = 0.0f, aW1 = 0.0f;   // pixel a (j = jp)
    float aG2 = 0.0f, aW2 = 0.0f;   // pixel b (j = jp+1)

    for (int pass = 0; pass < 2; ++pass) {
        // Phase B: stage this pass's pair-windows {g0, g1-g0}
        const float* __restrict__ srow = sino + n * (A_ * M_) + pass * (PASS_A * M_);
        for (int e = tid; e < PASS_A * W_; e += 512) {
            const int al = e / W_;
            const int k  = e - al * W_;
            const float off = tab[pass * PASS_A + al].z;
            const int lo = (int)(half - off);              // exact recovery
            const int i0 = min(max(lo + k,     0), M_ - 1);
            const int i1 = min(max(lo + k + 1, 0), M_ - 1);
            const float g0 = srow[al * M_ + i0];
            const float g1 = srow[al * M_ + i1];
            win2[e] = make_float2(g0, g1 - g0);
        }
        __syncthreads();

        // Phase C: this chunk's 45 angles, one ds_read2_b64 per angle per pair
        const int albase = chunk * CHUNK_A;
        #pragma unroll 5
        for (int q = 0; q < CHUNK_A; ++q) {
            const float4 tb = tab[pass * PASS_A + albase + q];
            float u1 = fmaf(gXc, tb.x, fmaf(ngyA, tb.y, tb.z));
            float u2 = u1 - tb.w;                 // pixel b: u - sin(theta)
            u1 = fminf(fmaxf(u1, 0.0f), 22.999f);
            u2 = fminf(fmaxf(u2, 0.0f), 22.999f);
            const int k1 = (int)u1;
            const int k2 = (int)u2;               // k1 in {k2, k2+1} always
            const float2* wrow = win2 + (albase + q) * W_;
            const float2 P0 = wrow[k2];
            const float2 P1 = wrow[k2 + 1];
            const float2 Pa = (k1 != k2) ? P1 : P0;
            const float w1 = __builtin_amdgcn_fractf(u1);
            const float w2 = __builtin_amdgcn_fractf(u2);
            aG1 += Pa.x;  aW1 = fmaf(w1, Pa.y, aW1);
            aG2 += P0.x;  aW2 = fmaf(w2, P0.y, aW2);
        }
        __syncthreads();   // win2 re-staged next pass / reused for reduction
    }

    // Cross-chunk reduction (reuse win2 space; all chunks synced above)
    float* red = (float*)win2;        // 3 * 128 * 2 floats = 3 KB
    if (chunk != 0) {
        red[((chunk - 1) * 128 + pp) * 2 + 0] = aG1 + aW1;
        red[((chunk - 1) * 128 + pp) * 2 + 1] = aG2 + aW2;
    }
    __syncthreads();
    if (chunk == 0) {
        float p1 = aG1 + aW1;
        float p2 = aG2 + aW2;
        #pragma unroll
        for (int q = 0; q < 3; ++q) {
            p1 += red[(q * 128 + pp) * 2 + 0];
            p2 += red[(q * 128 + pp) * 2 + 1];
        }
        // masks use the exact reference formula (bit-identical boundary)
        const float gyB = ((float)(jp + 1 - PS_ / 2) + cy) / half - 1.0f;
        const float in1 = (fmaf(gXc, gXc, gyA * gyA) <= 1.0f) ? 1.0f : 0.0f;
        const float in2 = (fmaf(gXc, gXc, gyB * gyB) <= 1.0f) ? 1.0f : 0.0f;
        const float scale = (float)(M_PI / (2.0 * (double)A_));
        float2 o;
        o.x = p1 * in1 * scale;
        o.y = p2 * in2 * scale;
        *(float2*)&out[(((n * NP_) + p) * PS_ + i) * PS_ + jp] = o;
    }
}

extern "C" void kernel_launch(void* const* d_in, const int* in_sizes, int n_in,
                              void* d_out, int out_size, void* d_ws, size_t ws_size,
                              hipStream_t stream) {
    const float* sino  = (const float*)d_in[0];
    const float* theta = (const float*)d_in[1];
    const float* cxs   = (const float*)d_in[2];
    const float* cys   = (const float*)d_in[3];
    float* out = (float*)d_out;

    const int blocks = N_ * NP_ * (PS_ * PS_ / 256);  // 1024
    fbp_pair<<<dim3(blocks), dim3(512), 0, stream>>>(sino, theta, cxs, cys, out);
}